// Round 1
// 119.035 us; speedup vs baseline: 1.1957x; 1.1957x over previous
//
#include <hip/hip_runtime.h>
#include <cstdint>
#include <cstddef>

#define N_CLS 80
#define TOPK 1000
#define POOL_N 2048
#define MCAP 512
#define BD 1024
#define DTB 128
#define LDSB_STRIDE 10  // u64 stride: 80B rows, 16B-aligned, 8-way not 32-way banked

// ---------------- K1: decode + score + per-class binning -------------------
// Row kept fully in registers (20x float4, all indices static after full
// unroll => no scratch). exp(x-mx) computed ONCE and kept in-place (expf is
// deterministic => bit-exact vs the old recompute passes). Sum is the strict
// left fold c=0..79; per-class q = sig*(e/s) comparison sequence identical to
// the original pass C => absmax 0.0 preserved.
__global__ __launch_bounds__(DTB) void decode_kernel(
    const float* __restrict__ reg, const float* __restrict__ obj,
    const float* __restrict__ cls, const float* __restrict__ grid,
    const float* __restrict__ anch, const float* __restrict__ strd,
    float* __restrict__ boxes, uint2* __restrict__ scs,
    int* __restrict__ gcnt, uint2* __restrict__ gpool, int N) {
  const int i = blockIdx.x * DTB + threadIdx.x;
  if (i >= N) return;

  const float4 r = ((const float4*)reg)[i];
  const float2 g = ((const float2*)grid)[i];
  const float2 aw = ((const float2*)anch)[i];
  const float st = strd[i];

  float cx = (1.0f / (1.0f + expf(-r.x)) + g.x) * st;
  float cy = (1.0f / (1.0f + expf(-r.y)) + g.y) * st;
  float w = expf(r.z) * aw.x;
  float h = expf(r.w) * aw.y;
  float b0 = fminf(fmaxf((cx - 0.5f * w) / 640.0f, 0.0f), 1.0f);
  float b1 = fminf(fmaxf((cy - 0.5f * h) / 640.0f, 0.0f), 1.0f);
  float b2 = fminf(fmaxf((cx + 0.5f * w) / 640.0f, 0.0f), 1.0f);
  float b3 = fminf(fmaxf((cy + 0.5f * h) / 640.0f, 0.0f), 1.0f);
  float4 bo; bo.x = b0; bo.y = b1; bo.z = b2; bo.w = b3;
  ((float4*)boxes)[i] = bo;

  const float4* cr = (const float4*)cls + (size_t)i * 20;
  float4 x[20];
#pragma unroll
  for (int q = 0; q < 20; ++q) x[q] = cr[q];

  // max over the row: fmaxf is exact & order-independent (no NaN inputs),
  // so the vectorized tree equals the original sequential chain bit-for-bit.
  float4 m4 = x[0];
#pragma unroll
  for (int q = 1; q < 20; ++q) {
    m4.x = fmaxf(m4.x, x[q].x); m4.y = fmaxf(m4.y, x[q].y);
    m4.z = fmaxf(m4.z, x[q].z); m4.w = fmaxf(m4.w, x[q].w);
  }
  float mx = fmaxf(fmaxf(m4.x, m4.y), fmaxf(m4.z, m4.w));

  // e_c = expf(x_c - mx), computed once, stored in place (independent ops
  // => pipelined; bit-identical to the old per-pass recompute).
#pragma unroll
  for (int q = 0; q < 20; ++q) {
    x[q].x = expf(x[q].x - mx); x[q].y = expf(x[q].y - mx);
    x[q].z = expf(x[q].z - mx); x[q].w = expf(x[q].w - mx);
  }

  // s: strict left fold, order c=0..79 (matches reference reduction order)
  float s = 0.0f;
#pragma unroll
  for (int q = 0; q < 20; ++q) {
    s += x[q].x; s += x[q].y; s += x[q].z; s += x[q].w;
  }

  float sig = 1.0f / (1.0f + expf(-obj[i]));

  // first-occurrence argmax of q = sig*(e/s), identical expressions & order
  float best = -1.0f; int bc = 0;
#pragma unroll
  for (int q = 0; q < 20; ++q) {
    float q0 = sig * (x[q].x / s);
    if (q0 > best) { best = q0; bc = 4 * q + 0; }
    float q1 = sig * (x[q].y / s);
    if (q1 > best) { best = q1; bc = 4 * q + 1; }
    float q2 = sig * (x[q].z / s);
    if (q2 > best) { best = q2; bc = 4 * q + 2; }
    float q3 = sig * (x[q].w / s);
    if (q3 > best) { best = q3; bc = 4 * q + 3; }
  }
  scs[i] = make_uint2(__float_as_uint(best), (unsigned)bc);
  if (best >= 0.001f) {
    int p = atomicAdd(&gcnt[bc * 16], 1);  // 64B-padded counters
    if (p < POOL_N) gpool[bc * POOL_N + p] = make_uint2(__float_as_uint(best), (unsigned)i);
  }
}

__device__ __forceinline__ unsigned long long kinit(int w, int m) {
  int lo = w << 6;
  return (m <= lo) ? 0ULL : ((m - lo >= 64) ? ~0ULL : ((1ULL << (m - lo)) - 1ULL));
}

// ---- K2 (fused): per-class rank sort + fillers + build + greedy + out -----
// Greedy is now a parallel Jacobi fixpoint of
//   keep[j] = valid[j] && !exists i<j : keep[i] && iou(i,j)>0.6
// (DAG recursion in j => Jacobi sweeps are exact after <= chain-depth rounds;
// "no change over a sweep" => fixpoint => identical to the sequential greedy).
// The suppression matrix is built TRANSPOSED (row j = suppressor bits i<j);
// the IoU formula is symmetric in (i,j) so every bit is bit-identical.
__global__ __launch_bounds__(BD) void nms_kernel(
    const float* __restrict__ boxes, const uint2* __restrict__ scs,
    const int* __restrict__ gcnt, const uint2* __restrict__ gpool,
    float* __restrict__ out, int N) {
  const int c = blockIdx.x;
  const int tid = threadIdx.x;

  __shared__ uint2 pool[POOL_N];                     // 16 KB
  __shared__ float svals[TOPK];                      // 4 KB
  __shared__ int sidx[TOPK];                         // 4 KB
  __shared__ __align__(16) float4 bxyz[TOPK];        // 16 KB
  __shared__ __align__(16) unsigned long long ldsB[MCAP * LDSB_STRIDE];  // 40 KB
  __shared__ unsigned char kp[TOPK];                 // fallback only
  __shared__ unsigned long long kpw[8];
  __shared__ __align__(16) unsigned long long kmbuf[2][8];
  __shared__ int chg;
  __shared__ int wsum[BD / 64 + 1];

  const int cnt = min(gcnt[c * 16], POOL_N);
  const int m = min(cnt, TOPK);
  for (int p = tid; p < cnt; p += BD) pool[p] = gpool[c * POOL_N + p];
  __syncthreads();

  // rank sort: value desc, ties -> index asc (== jax.lax.top_k order);
  // total order => independent of nondeterministic bin order.
  for (int e = tid; e < cnt; e += BD) {
    uint2 me = pool[e];
    float v = __uint_as_float(me.x);
    int idx = (int)me.y;
    int r = 0;
#pragma unroll 8
    for (int k = 0; k < cnt; ++k) {
      uint2 q = pool[k];
      float vk = __uint_as_float(q.x);
      r += (int)((vk > v) || (vk == v && (int)q.y < idx));
    }
    if (r < TOPK) { svals[r] = v; sidx[r] = idx; }
  }
  __syncthreads();

  // fillers: lowest-index non-matching anchors, ascending. ONE pass over the
  // first BD=1024 anchors: positives in any prefix <= m, so fillers in the
  // first 1000 >= 1000 - m = M.
  const int M = TOPK - m;
  if (M > 0) {
    int i = tid;
    bool f = false;
    if (i < N) {
      uint2 sc = scs[i];
      f = !((int)sc.y == c && __uint_as_float(sc.x) >= 0.001f);
    }
    unsigned long long mk = __ballot(f ? 1 : 0);
    int lane = tid & 63, wv = tid >> 6;
    int pre = __popcll(mk & ((1ULL << lane) - 1ULL));
    if (lane == 0) wsum[wv] = __popcll(mk);
    __syncthreads();
    if (tid == 0) {
      int acc = 0;
      for (int wq = 0; wq < BD / 64; ++wq) { int t2 = wsum[wq]; wsum[wq] = acc; acc += t2; }
    }
    __syncthreads();
    int pos = wsum[wv] + pre;
    if (f && pos < M) sidx[m + pos] = i;
  }
  __syncthreads();

  // gather boxes into LDS
  const float4* bf4 = (const float4*)boxes;
  for (int t = tid; t < TOPK; t += BD) bxyz[t] = bf4[sidx[t]];
  __syncthreads();

  const int W = (m + 63) >> 6;
  const bool fast = (m > 0) && (m <= MCAP);

  if (fast) {
    // build TRANSPOSED lower-triangle mask: row j, word w = bits of i<j with
    // iou(i,j)>0.6. Adjacent threads -> adjacent j => bxyz[i] broadcast.
    const int tasks = m * W;
    for (int q = tid; q < tasks; q += BD) {
      int w = q / m;
      int j = q - w * m;
      unsigned long long bits = 0ULL;
      if (w <= (j >> 6)) {
        float4 jb = bxyz[j];
        float aj = (jb.z - jb.x) * (jb.w - jb.y);
        int i0 = w << 6, iend = min(i0 + 64, j);  // i < j strictly
        for (int i = i0; i < iend; ++i) {
          float4 ib = bxyz[i];
          float ai = (ib.z - ib.x) * (ib.w - ib.y);
          float xx1 = fmaxf(ib.x, jb.x), yy1 = fmaxf(ib.y, jb.y);
          float xx2 = fminf(ib.z, jb.z), yy2 = fminf(ib.w, jb.w);
          float ww = fmaxf(1e-28f, xx2 - xx1), hh = fmaxf(1e-28f, yy2 - yy1);
          float inter = ww * hh;
          float iou = inter / (ai + aj - inter + 1e-14f);
          if (iou > 0.6f) bits |= (1ULL << (i - i0));
        }
      }
      ldsB[(size_t)j * LDSB_STRIDE + w] = bits;
    }
    __syncthreads();

    // cache my suppressor row in 16 VGPRs; init km = all m rows kept
    ulonglong2 ta, tb, tc, td;
    ta = tb = tc = td = make_ulonglong2(0ULL, 0ULL);
    if (tid < m) {
      const ulonglong2* rp = (const ulonglong2*)&ldsB[(size_t)tid * LDSB_STRIDE];
      ta = rp[0]; tb = rp[1]; tc = rp[2]; td = rp[3];
    }
    if (tid < 8) kmbuf[0][tid] = kinit(tid, m);
    __syncthreads();

    // Jacobi sweeps to fixpoint (<= depth+1 rounds, typically ~3-6)
    int cur = 0;
    for (;;) {
      bool keep = false;
      if (tid < m) {
        unsigned long long sup =
            (ta.x & kmbuf[cur][0]) | (ta.y & kmbuf[cur][1]) |
            (tb.x & kmbuf[cur][2]) | (tb.y & kmbuf[cur][3]) |
            (tc.x & kmbuf[cur][4]) | (tc.y & kmbuf[cur][5]) |
            (td.x & kmbuf[cur][6]) | (td.y & kmbuf[cur][7]);
        keep = (sup == 0ULL);
      }
      unsigned long long bl = __ballot(keep ? 1 : 0);
      int wv = tid >> 6;
      if ((tid & 63) == 0 && wv < 8) kmbuf[cur ^ 1][wv] = bl;
      __syncthreads();
      if (tid == 0) {
        int c2 = 0;
        for (int u = 0; u < 8; ++u) c2 |= (kmbuf[0][u] != kmbuf[1][u]) ? 1 : 0;
        chg = c2;
      }
      __syncthreads();
      cur ^= 1;
      if (!chg) break;
    }
    if (tid < 8) kpw[tid] = kmbuf[cur][tid];
    __syncthreads();
  } else {
    // fallback (m == 0 or m > MCAP): serial barrier loop — always correct
    for (int t = tid; t < TOPK; t += BD) kp[t] = (t < m) ? 1 : 0;
    __syncthreads();
    for (int i = 0; i < m; ++i) {
      if (kp[i]) {
        float4 rb = bxyz[i];
        float ai = (rb.z - rb.x) * (rb.w - rb.y);
        for (int j = i + 1 + tid; j < m; j += BD) {
          if (kp[j]) {
            float4 jb = bxyz[j];
            float aj = (jb.z - jb.x) * (jb.w - jb.y);
            float xx1 = fmaxf(rb.x, jb.x), yy1 = fmaxf(rb.y, jb.y);
            float xx2 = fminf(rb.z, jb.z), yy2 = fminf(rb.w, jb.w);
            float ww = fmaxf(1e-28f, xx2 - xx1), hh = fmaxf(1e-28f, yy2 - yy1);
            float inter = ww * hh;
            float iou = inter / (ai + aj - inter + 1e-14f);
            if (iou > 0.6f) kp[j] = 0;
          }
        }
      }
      __syncthreads();
    }
  }

  // outputs: boxes [80,1000,4], scores*keep [80,1000], keep [80,1000]
  float* outB = out;
  float* outS = out + N_CLS * TOPK * 4;
  float* outK = outS + N_CLS * TOPK;
  for (int t = tid; t < TOPK; t += BD) {
    float k = 0.0f;
    if (t < m)
      k = fast ? (float)((kpw[t >> 6] >> (t & 63)) & 1ULL) : (float)kp[t];
    float v = (t < m) ? svals[t] : -1.0f;
    ((float4*)outB)[c * TOPK + t] = bxyz[t];
    outS[c * TOPK + t] = v * k;
    outK[c * TOPK + t] = k;
  }
}

extern "C" void kernel_launch(void* const* d_in, const int* in_sizes, int n_in,
                              void* d_out, int out_size, void* d_ws, size_t ws_size,
                              hipStream_t stream) {
  const float* reg  = (const float*)d_in[0];
  const float* obj  = (const float*)d_in[1];
  const float* cls  = (const float*)d_in[2];
  const float* grid = (const float*)d_in[3];
  const float* anch = (const float*)d_in[4];
  const float* strd = (const float*)d_in[5];
  const int N = in_sizes[0] / 4;  // 25200

  char* w8 = (char*)d_ws;
  size_t off = 0;
  float* boxes = (float*)(w8 + off); off += (size_t)N * 16;
  uint2* scs   = (uint2*)(w8 + off); off += (size_t)N * 8;
  int* gcnt    = (int*)(w8 + off);   off += 80 * 16 * 4;    // 64B-padded counters
  uint2* gpool = (uint2*)(w8 + off); off += (size_t)N_CLS * POOL_N * 8;
  float* out = (float*)d_out;

  hipMemsetAsync(gcnt, 0, 80 * 16 * 4, stream);
  decode_kernel<<<(N + DTB - 1) / DTB, DTB, 0, stream>>>(
      reg, obj, cls, grid, anch, strd, boxes, scs, gcnt, gpool, N);
  nms_kernel<<<N_CLS, BD, 0, stream>>>(boxes, scs, gcnt, gpool, out, N);
}

// Round 2
// 118.476 us; speedup vs baseline: 1.2013x; 1.0047x over previous
//
#include <hip/hip_runtime.h>
#include <cstdint>
#include <cstddef>

#define N_CLS 80
#define TOPK 1000
#define POOL_N 2048
#define MCAP 512
#define BD 1024
#define DTB 128
#define LDSB_STRIDE 10  // u64 stride: 80B rows, 16B-aligned, 8-way not 32-way banked

// ---------------- K1: decode + score (NO atomics, NO pooling) --------------
// R1 post-mortem: duration was pinned at ~41us by the contended global
// atomicAdd tail (25200 returning atomics over 80 counter lines), invariant
// under ALU restructuring. Pool building moved into K2 (per-class scan of
// scs, block-local compaction). decode now only computes and stores.
__global__ __launch_bounds__(DTB) void decode_kernel(
    const float* __restrict__ reg, const float* __restrict__ obj,
    const float* __restrict__ cls, const float* __restrict__ grid,
    const float* __restrict__ anch, const float* __restrict__ strd,
    float* __restrict__ boxes, uint2* __restrict__ scs, int N) {
  const int i = blockIdx.x * DTB + threadIdx.x;
  if (i >= N) return;

  const float4 r = ((const float4*)reg)[i];
  const float2 g = ((const float2*)grid)[i];
  const float2 aw = ((const float2*)anch)[i];
  const float st = strd[i];

  float cx = (1.0f / (1.0f + expf(-r.x)) + g.x) * st;
  float cy = (1.0f / (1.0f + expf(-r.y)) + g.y) * st;
  float w = expf(r.z) * aw.x;
  float h = expf(r.w) * aw.y;
  float b0 = fminf(fmaxf((cx - 0.5f * w) / 640.0f, 0.0f), 1.0f);
  float b1 = fminf(fmaxf((cy - 0.5f * h) / 640.0f, 0.0f), 1.0f);
  float b2 = fminf(fmaxf((cx + 0.5f * w) / 640.0f, 0.0f), 1.0f);
  float b3 = fminf(fmaxf((cy + 0.5f * h) / 640.0f, 0.0f), 1.0f);
  float4 bo; bo.x = b0; bo.y = b1; bo.z = b2; bo.w = b3;
  ((float4*)boxes)[i] = bo;

  const float4* cr = (const float4*)cls + (size_t)i * 20;
  float4 x[20];
#pragma unroll
  for (int q = 0; q < 20; ++q) x[q] = cr[q];

  // max: fmaxf is exact & order-independent (no NaNs) => tree == chain
  float4 m4 = x[0];
#pragma unroll
  for (int q = 1; q < 20; ++q) {
    m4.x = fmaxf(m4.x, x[q].x); m4.y = fmaxf(m4.y, x[q].y);
    m4.z = fmaxf(m4.z, x[q].z); m4.w = fmaxf(m4.w, x[q].w);
  }
  float mx = fmaxf(fmaxf(m4.x, m4.y), fmaxf(m4.z, m4.w));

  // e_c = expf(x_c - mx) once, in place (deterministic => bit-exact)
#pragma unroll
  for (int q = 0; q < 20; ++q) {
    x[q].x = expf(x[q].x - mx); x[q].y = expf(x[q].y - mx);
    x[q].z = expf(x[q].z - mx); x[q].w = expf(x[q].w - mx);
  }

  // s: strict left fold c=0..79 (matches verified reduction order)
  float s = 0.0f;
#pragma unroll
  for (int q = 0; q < 20; ++q) {
    s += x[q].x; s += x[q].y; s += x[q].z; s += x[q].w;
  }

  float sig = 1.0f / (1.0f + expf(-obj[i]));

  // first-occurrence argmax of q = sig*(e/s), identical expressions & order
  float best = -1.0f; int bc = 0;
#pragma unroll
  for (int q = 0; q < 20; ++q) {
    float q0 = sig * (x[q].x / s);
    if (q0 > best) { best = q0; bc = 4 * q + 0; }
    float q1 = sig * (x[q].y / s);
    if (q1 > best) { best = q1; bc = 4 * q + 1; }
    float q2 = sig * (x[q].z / s);
    if (q2 > best) { best = q2; bc = 4 * q + 2; }
    float q3 = sig * (x[q].w / s);
    if (q3 > best) { best = q3; bc = 4 * q + 3; }
  }
  scs[i] = make_uint2(__float_as_uint(best), (unsigned)bc);
}

__device__ __forceinline__ unsigned long long kinit(int w, int m) {
  int lo = w << 6;
  return (m <= lo) ? 0ULL : ((m - lo >= 64) ? ~0ULL : ((1ULL << (m - lo)) - 1ULL));
}

// ---- K2: per-class pool scan + rank sort + fillers + build + Jacobi + out -
// Pool built here by scanning scs (L2-resident, coalesced) and compacting
// positives with a block-local LDS counter. Fill order is nondeterministic
// but the rank sort (value desc, index asc == jax.lax.top_k order) imposes a
// total order => outputs independent of fill order.
__global__ __launch_bounds__(BD) void nms_kernel(
    const float* __restrict__ boxes, const uint2* __restrict__ scs,
    float* __restrict__ out, int N) {
  const int c = blockIdx.x;
  const int tid = threadIdx.x;

  __shared__ uint2 pool[POOL_N];                     // 16 KB
  __shared__ int pcnt;
  __shared__ float svals[TOPK];                      // 4 KB
  __shared__ int sidx[TOPK];                         // 4 KB
  __shared__ __align__(16) float4 bxyz[TOPK];        // 16 KB
  __shared__ __align__(16) unsigned long long ldsB[MCAP * LDSB_STRIDE];  // 40 KB
  __shared__ unsigned char kp[TOPK];                 // fallback only
  __shared__ unsigned long long kpw[8];
  __shared__ __align__(16) unsigned long long kmbuf[2][8];
  __shared__ int chg;
  __shared__ int wsum[BD / 64 + 1];

  if (tid == 0) pcnt = 0;
  __syncthreads();

  // scan all anchors, compact this class's positives (same predicate the
  // old decode used for binning: argmax class == c && best >= 0.001)
  for (int i = tid; i < N; i += BD) {
    uint2 sc = scs[i];
    if ((int)sc.y == c && __uint_as_float(sc.x) >= 0.001f) {
      int p = atomicAdd(&pcnt, 1);
      if (p < POOL_N) pool[p] = make_uint2(sc.x, (unsigned)i);
    }
  }
  __syncthreads();

  const int cnt = min(pcnt, POOL_N);
  const int m = min(cnt, TOPK);

  // rank sort: value desc, ties -> index asc (== jax.lax.top_k order)
  for (int e = tid; e < cnt; e += BD) {
    uint2 me = pool[e];
    float v = __uint_as_float(me.x);
    int idx = (int)me.y;
    int r = 0;
#pragma unroll 8
    for (int k = 0; k < cnt; ++k) {
      uint2 q = pool[k];
      float vk = __uint_as_float(q.x);
      r += (int)((vk > v) || (vk == v && (int)q.y < idx));
    }
    if (r < TOPK) { svals[r] = v; sidx[r] = idx; }
  }
  __syncthreads();

  // fillers: lowest-index non-matching anchors, ascending. ONE pass over the
  // first BD=1024 anchors: positives in any prefix <= m, so fillers in the
  // first 1000 >= 1000 - m = M.
  const int M = TOPK - m;
  if (M > 0) {
    int i = tid;
    bool f = false;
    if (i < N) {
      uint2 sc = scs[i];
      f = !((int)sc.y == c && __uint_as_float(sc.x) >= 0.001f);
    }
    unsigned long long mk = __ballot(f ? 1 : 0);
    int lane = tid & 63, wv = tid >> 6;
    int pre = __popcll(mk & ((1ULL << lane) - 1ULL));
    if (lane == 0) wsum[wv] = __popcll(mk);
    __syncthreads();
    if (tid == 0) {
      int acc = 0;
      for (int wq = 0; wq < BD / 64; ++wq) { int t2 = wsum[wq]; wsum[wq] = acc; acc += t2; }
    }
    __syncthreads();
    int pos = wsum[wv] + pre;
    if (f && pos < M) sidx[m + pos] = i;
  }
  __syncthreads();

  // gather boxes into LDS
  const float4* bf4 = (const float4*)boxes;
  for (int t = tid; t < TOPK; t += BD) bxyz[t] = bf4[sidx[t]];
  __syncthreads();

  const int W = (m + 63) >> 6;
  const bool fast = (m > 0) && (m <= MCAP);

  if (fast) {
    // build TRANSPOSED lower-triangle mask: row j, word w = bits of i<j with
    // iou(i,j)>0.6 (IoU symmetric in (i,j) => bits bit-identical to greedy)
    const int tasks = m * W;
    for (int q = tid; q < tasks; q += BD) {
      int w = q / m;
      int j = q - w * m;
      unsigned long long bits = 0ULL;
      if (w <= (j >> 6)) {
        float4 jb = bxyz[j];
        float aj = (jb.z - jb.x) * (jb.w - jb.y);
        int i0 = w << 6, iend = min(i0 + 64, j);  // i < j strictly
        for (int i = i0; i < iend; ++i) {
          float4 ib = bxyz[i];
          float ai = (ib.z - ib.x) * (ib.w - ib.y);
          float xx1 = fmaxf(ib.x, jb.x), yy1 = fmaxf(ib.y, jb.y);
          float xx2 = fminf(ib.z, jb.z), yy2 = fminf(ib.w, jb.w);
          float ww = fmaxf(1e-28f, xx2 - xx1), hh = fmaxf(1e-28f, yy2 - yy1);
          float inter = ww * hh;
          float iou = inter / (ai + aj - inter + 1e-14f);
          if (iou > 0.6f) bits |= (1ULL << (i - i0));
        }
      }
      ldsB[(size_t)j * LDSB_STRIDE + w] = bits;
    }
    __syncthreads();

    // cache my suppressor row in 16 VGPRs; init km = all m rows kept
    ulonglong2 ta, tb, tc, td;
    ta = tb = tc = td = make_ulonglong2(0ULL, 0ULL);
    if (tid < m) {
      const ulonglong2* rp = (const ulonglong2*)&ldsB[(size_t)tid * LDSB_STRIDE];
      ta = rp[0]; tb = rp[1]; tc = rp[2]; td = rp[3];
    }
    if (tid < 8) kmbuf[0][tid] = kinit(tid, m);
    __syncthreads();

    // Jacobi sweeps to fixpoint (exact: DAG recursion in j; "no change over
    // a full sweep" => fixpoint => identical keep mask to sequential greedy)
    int cur = 0;
    for (;;) {
      bool keep = false;
      if (tid < m) {
        unsigned long long sup =
            (ta.x & kmbuf[cur][0]) | (ta.y & kmbuf[cur][1]) |
            (tb.x & kmbuf[cur][2]) | (tb.y & kmbuf[cur][3]) |
            (tc.x & kmbuf[cur][4]) | (tc.y & kmbuf[cur][5]) |
            (td.x & kmbuf[cur][6]) | (td.y & kmbuf[cur][7]);
        keep = (sup == 0ULL);
      }
      unsigned long long bl = __ballot(keep ? 1 : 0);
      int wv = tid >> 6;
      if ((tid & 63) == 0 && wv < 8) kmbuf[cur ^ 1][wv] = bl;
      __syncthreads();
      if (tid == 0) {
        int c2 = 0;
        for (int u = 0; u < 8; ++u) c2 |= (kmbuf[0][u] != kmbuf[1][u]) ? 1 : 0;
        chg = c2;
      }
      __syncthreads();
      cur ^= 1;
      if (!chg) break;
    }
    if (tid < 8) kpw[tid] = kmbuf[cur][tid];
    __syncthreads();
  } else {
    // fallback (m == 0 or m > MCAP): serial barrier loop — always correct
    for (int t = tid; t < TOPK; t += BD) kp[t] = (t < m) ? 1 : 0;
    __syncthreads();
    for (int i = 0; i < m; ++i) {
      if (kp[i]) {
        float4 rb = bxyz[i];
        float ai = (rb.z - rb.x) * (rb.w - rb.y);
        for (int j = i + 1 + tid; j < m; j += BD) {
          if (kp[j]) {
            float4 jb = bxyz[j];
            float aj = (jb.z - jb.x) * (jb.w - jb.y);
            float xx1 = fmaxf(rb.x, jb.x), yy1 = fmaxf(rb.y, jb.y);
            float xx2 = fminf(rb.z, jb.z), yy2 = fminf(rb.w, jb.w);
            float ww = fmaxf(1e-28f, xx2 - xx1), hh = fmaxf(1e-28f, yy2 - yy1);
            float inter = ww * hh;
            float iou = inter / (ai + aj - inter + 1e-14f);
            if (iou > 0.6f) kp[j] = 0;
          }
        }
      }
      __syncthreads();
    }
  }

  // outputs: boxes [80,1000,4], scores*keep [80,1000], keep [80,1000]
  float* outB = out;
  float* outS = out + N_CLS * TOPK * 4;
  float* outK = outS + N_CLS * TOPK;
  for (int t = tid; t < TOPK; t += BD) {
    float k = 0.0f;
    if (t < m)
      k = fast ? (float)((kpw[t >> 6] >> (t & 63)) & 1ULL) : (float)kp[t];
    float v = (t < m) ? svals[t] : -1.0f;
    ((float4*)outB)[c * TOPK + t] = bxyz[t];
    outS[c * TOPK + t] = v * k;
    outK[c * TOPK + t] = k;
  }
}

extern "C" void kernel_launch(void* const* d_in, const int* in_sizes, int n_in,
                              void* d_out, int out_size, void* d_ws, size_t ws_size,
                              hipStream_t stream) {
  const float* reg  = (const float*)d_in[0];
  const float* obj  = (const float*)d_in[1];
  const float* cls  = (const float*)d_in[2];
  const float* grid = (const float*)d_in[3];
  const float* anch = (const float*)d_in[4];
  const float* strd = (const float*)d_in[5];
  const int N = in_sizes[0] / 4;  // 25200

  char* w8 = (char*)d_ws;
  size_t off = 0;
  float* boxes = (float*)(w8 + off); off += (size_t)N * 16;
  uint2* scs   = (uint2*)(w8 + off); off += (size_t)N * 8;
  float* out = (float*)d_out;

  decode_kernel<<<(N + DTB - 1) / DTB, DTB, 0, stream>>>(
      reg, obj, cls, grid, anch, strd, boxes, scs, N);
  nms_kernel<<<N_CLS, BD, 0, stream>>>(boxes, scs, out, N);
}

// Round 3
// 115.685 us; speedup vs baseline: 1.2303x; 1.0241x over previous
//
#include <hip/hip_runtime.h>
#include <cstdint>
#include <cstddef>

#define N_CLS 80
#define TOPK 1000
#define POOL_N 2048
#define MCAP 512
#define BD 1024
#define DTB 128
#define LDSB_STRIDE 10  // u64 stride: 80B rows, 16B-aligned, 8-way not 32-way banked
#define SCAN_CHUNK 13   // prefetch depth: 13 loads in flight => ~2 latencies/chunk

// ---------------- K1: decode + score (NO atomics, NO pooling) --------------
__global__ __launch_bounds__(DTB) void decode_kernel(
    const float* __restrict__ reg, const float* __restrict__ obj,
    const float* __restrict__ cls, const float* __restrict__ grid,
    const float* __restrict__ anch, const float* __restrict__ strd,
    float* __restrict__ boxes, uint2* __restrict__ scs, int N) {
  const int i = blockIdx.x * DTB + threadIdx.x;
  if (i >= N) return;

  const float4 r = ((const float4*)reg)[i];
  const float2 g = ((const float2*)grid)[i];
  const float2 aw = ((const float2*)anch)[i];
  const float st = strd[i];

  float cx = (1.0f / (1.0f + expf(-r.x)) + g.x) * st;
  float cy = (1.0f / (1.0f + expf(-r.y)) + g.y) * st;
  float w = expf(r.z) * aw.x;
  float h = expf(r.w) * aw.y;
  float b0 = fminf(fmaxf((cx - 0.5f * w) / 640.0f, 0.0f), 1.0f);
  float b1 = fminf(fmaxf((cy - 0.5f * h) / 640.0f, 0.0f), 1.0f);
  float b2 = fminf(fmaxf((cx + 0.5f * w) / 640.0f, 0.0f), 1.0f);
  float b3 = fminf(fmaxf((cy + 0.5f * h) / 640.0f, 0.0f), 1.0f);
  float4 bo; bo.x = b0; bo.y = b1; bo.z = b2; bo.w = b3;
  ((float4*)boxes)[i] = bo;

  const float4* cr = (const float4*)cls + (size_t)i * 20;
  float4 x[20];
#pragma unroll
  for (int q = 0; q < 20; ++q) x[q] = cr[q];

  // max: fmaxf is exact & order-independent (no NaNs) => tree == chain
  float4 m4 = x[0];
#pragma unroll
  for (int q = 1; q < 20; ++q) {
    m4.x = fmaxf(m4.x, x[q].x); m4.y = fmaxf(m4.y, x[q].y);
    m4.z = fmaxf(m4.z, x[q].z); m4.w = fmaxf(m4.w, x[q].w);
  }
  float mx = fmaxf(fmaxf(m4.x, m4.y), fmaxf(m4.z, m4.w));

  // e_c = expf(x_c - mx) once, in place (deterministic => bit-exact)
#pragma unroll
  for (int q = 0; q < 20; ++q) {
    x[q].x = expf(x[q].x - mx); x[q].y = expf(x[q].y - mx);
    x[q].z = expf(x[q].z - mx); x[q].w = expf(x[q].w - mx);
  }

  // s: strict left fold c=0..79 (matches verified reduction order)
  float s = 0.0f;
#pragma unroll
  for (int q = 0; q < 20; ++q) {
    s += x[q].x; s += x[q].y; s += x[q].z; s += x[q].w;
  }

  float sig = 1.0f / (1.0f + expf(-obj[i]));

  // first-occurrence argmax of q = sig*(e/s), identical expressions & order
  float best = -1.0f; int bc = 0;
#pragma unroll
  for (int q = 0; q < 20; ++q) {
    float q0 = sig * (x[q].x / s);
    if (q0 > best) { best = q0; bc = 4 * q + 0; }
    float q1 = sig * (x[q].y / s);
    if (q1 > best) { best = q1; bc = 4 * q + 1; }
    float q2 = sig * (x[q].z / s);
    if (q2 > best) { best = q2; bc = 4 * q + 2; }
    float q3 = sig * (x[q].w / s);
    if (q3 > best) { best = q3; bc = 4 * q + 3; }
  }
  scs[i] = make_uint2(__float_as_uint(best), (unsigned)bc);
}

__device__ __forceinline__ unsigned long long kinit(int w, int m) {
  int lo = w << 6;
  return (m <= lo) ? 0ULL : ((m - lo >= 64) ? ~0ULL : ((1ULL << (m - lo)) - 1ULL));
}

// ---- K2: per-class pool scan + rank sort + fillers + build + Jacobi + out -
// R2 post-mortem: the scan was 25 SERIALIZED ~2000-cyc loads (rolled loop,
// vmcnt(0) each iter) => ~25us. Now chunked: SCAN_CHUNK independent
// predicated loads issued into registers first (one latency per chunk), then
// processed. Pool fill order still nondeterministic; rank sort imposes the
// total order => outputs unchanged.
__global__ __launch_bounds__(BD) void nms_kernel(
    const float* __restrict__ boxes, const uint2* __restrict__ scs,
    float* __restrict__ out, int N) {
  const int c = blockIdx.x;
  const int tid = threadIdx.x;

  __shared__ uint2 pool[POOL_N];                     // 16 KB
  __shared__ int pcnt;
  __shared__ float svals[TOPK];                      // 4 KB
  __shared__ int sidx[TOPK];                         // 4 KB
  __shared__ __align__(16) float4 bxyz[TOPK];        // 16 KB
  __shared__ __align__(16) unsigned long long ldsB[MCAP * LDSB_STRIDE];  // 40 KB
  __shared__ unsigned char kp[TOPK];                 // fallback only
  __shared__ __align__(16) unsigned long long kmbuf[2][8];
  __shared__ int wsum[BD / 64 + 1];

  if (tid == 0) pcnt = 0;
  __syncthreads();

  // chunked prefetch scan: issue SCAN_CHUNK independent loads, then process
  for (int b0 = 0; b0 < N; b0 += SCAN_CHUNK * BD) {
    uint2 buf[SCAN_CHUNK];
#pragma unroll
    for (int k = 0; k < SCAN_CHUNK; ++k) {
      int i = b0 + k * BD + tid;
      buf[k] = (i < N) ? scs[i] : make_uint2(0u, 0xFFFFFFFFu);
    }
#pragma unroll
    for (int k = 0; k < SCAN_CHUNK; ++k) {
      int i = b0 + k * BD + tid;
      uint2 sc = buf[k];
      if ((int)sc.y == c && __uint_as_float(sc.x) >= 0.001f) {
        int p = atomicAdd(&pcnt, 1);
        if (p < POOL_N) pool[p] = make_uint2(sc.x, (unsigned)i);
      }
    }
  }
  __syncthreads();

  const int cnt = min(pcnt, POOL_N);
  const int m = min(cnt, TOPK);

  // rank sort: value desc, ties -> index asc (== jax.lax.top_k order)
  for (int e = tid; e < cnt; e += BD) {
    uint2 me = pool[e];
    float v = __uint_as_float(me.x);
    int idx = (int)me.y;
    int r = 0;
#pragma unroll 8
    for (int k = 0; k < cnt; ++k) {
      uint2 q = pool[k];
      float vk = __uint_as_float(q.x);
      r += (int)((vk > v) || (vk == v && (int)q.y < idx));
    }
    if (r < TOPK) { svals[r] = v; sidx[r] = idx; }
  }
  __syncthreads();

  // fillers: lowest-index non-matching anchors, ascending. ONE pass over the
  // first BD=1024 anchors suffices (positives in any prefix <= m).
  const int M = TOPK - m;
  if (M > 0) {
    int i = tid;
    bool f = false;
    if (i < N) {
      uint2 sc = scs[i];
      f = !((int)sc.y == c && __uint_as_float(sc.x) >= 0.001f);
    }
    unsigned long long mk = __ballot(f ? 1 : 0);
    int lane = tid & 63, wv = tid >> 6;
    int pre = __popcll(mk & ((1ULL << lane) - 1ULL));
    if (lane == 0) wsum[wv] = __popcll(mk);
    __syncthreads();
    if (tid == 0) {
      int acc = 0;
      for (int wq = 0; wq < BD / 64; ++wq) { int t2 = wsum[wq]; wsum[wq] = acc; acc += t2; }
    }
    __syncthreads();
    int pos = wsum[wv] + pre;
    if (f && pos < M) sidx[m + pos] = i;
  }
  __syncthreads();

  // gather boxes into LDS
  const float4* bf4 = (const float4*)boxes;
  for (int t = tid; t < TOPK; t += BD) bxyz[t] = bf4[sidx[t]];
  __syncthreads();

  const int W = (m + 63) >> 6;
  const bool fast = (m > 0) && (m <= MCAP);
  int cur = 0;

  if (fast) {
    // build TRANSPOSED lower-triangle mask: row j, word w = bits of i<j with
    // iou(i,j)>0.6 (IoU symmetric in (i,j) => bits bit-identical to greedy)
    const int tasks = m * W;
    for (int q = tid; q < tasks; q += BD) {
      int w = q / m;
      int j = q - w * m;
      unsigned long long bits = 0ULL;
      if (w <= (j >> 6)) {
        float4 jb = bxyz[j];
        float aj = (jb.z - jb.x) * (jb.w - jb.y);
        int i0 = w << 6, iend = min(i0 + 64, j);  // i < j strictly
        for (int i = i0; i < iend; ++i) {
          float4 ib = bxyz[i];
          float ai = (ib.z - ib.x) * (ib.w - ib.y);
          float xx1 = fmaxf(ib.x, jb.x), yy1 = fmaxf(ib.y, jb.y);
          float xx2 = fminf(ib.z, jb.z), yy2 = fminf(ib.w, jb.w);
          float ww = fmaxf(1e-28f, xx2 - xx1), hh = fmaxf(1e-28f, yy2 - yy1);
          float inter = ww * hh;
          float iou = inter / (ai + aj - inter + 1e-14f);
          if (iou > 0.6f) bits |= (1ULL << (i - i0));
        }
      }
      ldsB[(size_t)j * LDSB_STRIDE + w] = bits;
    }
    __syncthreads();

    // cache my suppressor row in 16 VGPRs; init km = all m rows kept
    ulonglong2 ta, tb, tc, td;
    ta = tb = tc = td = make_ulonglong2(0ULL, 0ULL);
    if (tid < m) {
      const ulonglong2* rp = (const ulonglong2*)&ldsB[(size_t)tid * LDSB_STRIDE];
      ta = rp[0]; tb = rp[1]; tc = rp[2]; td = rp[3];
    }
    if (tid < 8) kmbuf[0][tid] = kinit(tid, m);
    __syncthreads();

    // Jacobi sweeps to fixpoint. Exact: the sweep function's fixpoint is
    // unique (strong induction on row index) and equals the greedy mask.
    // One barrier per round via __syncthreads_or change detection.
    for (;;) {
      bool keep = false;
      if (tid < m) {
        unsigned long long sup =
            (ta.x & kmbuf[cur][0]) | (ta.y & kmbuf[cur][1]) |
            (tb.x & kmbuf[cur][2]) | (tb.y & kmbuf[cur][3]) |
            (tc.x & kmbuf[cur][4]) | (tc.y & kmbuf[cur][5]) |
            (td.x & kmbuf[cur][6]) | (td.y & kmbuf[cur][7]);
        keep = (sup == 0ULL);
      }
      bool old = (tid < m) &&
                 ((kmbuf[cur][tid >> 6] >> (tid & 63)) & 1ULL);
      unsigned long long bl = __ballot(keep ? 1 : 0);
      int wv = tid >> 6;
      if ((tid & 63) == 0 && wv < 8) kmbuf[cur ^ 1][wv] = bl;
      int any = __syncthreads_or((int)(keep != old));
      cur ^= 1;
      if (!any) break;
    }
  } else {
    // fallback (m == 0 or m > MCAP): serial barrier loop — always correct
    for (int t = tid; t < TOPK; t += BD) kp[t] = (t < m) ? 1 : 0;
    __syncthreads();
    for (int i = 0; i < m; ++i) {
      if (kp[i]) {
        float4 rb = bxyz[i];
        float ai = (rb.z - rb.x) * (rb.w - rb.y);
        for (int j = i + 1 + tid; j < m; j += BD) {
          if (kp[j]) {
            float4 jb = bxyz[j];
            float aj = (jb.z - jb.x) * (jb.w - jb.y);
            float xx1 = fmaxf(rb.x, jb.x), yy1 = fmaxf(rb.y, jb.y);
            float xx2 = fminf(rb.z, jb.z), yy2 = fminf(rb.w, jb.w);
            float ww = fmaxf(1e-28f, xx2 - xx1), hh = fmaxf(1e-28f, yy2 - yy1);
            float inter = ww * hh;
            float iou = inter / (ai + aj - inter + 1e-14f);
            if (iou > 0.6f) kp[j] = 0;
          }
        }
      }
      __syncthreads();
    }
  }

  // outputs: boxes [80,1000,4], scores*keep [80,1000], keep [80,1000]
  float* outB = out;
  float* outS = out + N_CLS * TOPK * 4;
  float* outK = outS + N_CLS * TOPK;
  for (int t = tid; t < TOPK; t += BD) {
    float k = 0.0f;
    if (t < m)
      k = fast ? (float)((kmbuf[cur][t >> 6] >> (t & 63)) & 1ULL)
               : (float)kp[t];
    float v = (t < m) ? svals[t] : -1.0f;
    ((float4*)outB)[c * TOPK + t] = bxyz[t];
    outS[c * TOPK + t] = v * k;
    outK[c * TOPK + t] = k;
  }
}

extern "C" void kernel_launch(void* const* d_in, const int* in_sizes, int n_in,
                              void* d_out, int out_size, void* d_ws, size_t ws_size,
                              hipStream_t stream) {
  const float* reg  = (const float*)d_in[0];
  const float* obj  = (const float*)d_in[1];
  const float* cls  = (const float*)d_in[2];
  const float* grid = (const float*)d_in[3];
  const float* anch = (const float*)d_in[4];
  const float* strd = (const float*)d_in[5];
  const int N = in_sizes[0] / 4;  // 25200

  char* w8 = (char*)d_ws;
  size_t off = 0;
  float* boxes = (float*)(w8 + off); off += (size_t)N * 16;
  uint2* scs   = (uint2*)(w8 + off); off += (size_t)N * 8;
  float* out = (float*)d_out;

  decode_kernel<<<(N + DTB - 1) / DTB, DTB, 0, stream>>>(
      reg, obj, cls, grid, anch, strd, boxes, scs, N);
  nms_kernel<<<N_CLS, BD, 0, stream>>>(boxes, scs, out, N);
}